// Round 6
// baseline (273.287 us; speedup 1.0000x reference)
//
#include <hip/hip_runtime.h>
#include <math.h>

// QueryDynamicAttention: B=16, N=1024, D=768, MU=768, R=16, DR=48
// out = (x * sigmoid(channel_att)) * sigmoid(spatial)
// Hypernet GEMM (mu @ Wg*, 226 MB streamed) is HBM-bound. Round 6:
// the compiler collapsed register-prefetch pipelines 3x -> switch mechanism:
// W staged via global_load_lds DMA rings (no dest reg -> cannot serialize),
// explicit vmcnt(7) ring discipline; mu on the scalar pipe (s_load, uniform
// addressing). K-split x2 across grid with f32 partials merged by k_redW.

#define B_  16
#define N_  1024
#define D_  768
#define MU_ 768

__device__ __forceinline__ void dma16(const float* g, float* l) {
    __builtin_amdgcn_global_load_lds(
        (__attribute__((address_space(1))) void*)(g),
        (__attribute__((address_space(3))) void*)(l), 16, 0, 0);
}

// ---------------------------------------------------------------------------
// k_pool: avg/max pooling partials over N (32 chunks of 32 tokens) + mu transpose
__global__ __launch_bounds__(192) void k_pool(
    const float* __restrict__ x, const float* __restrict__ mu,
    float* __restrict__ mu_t, float* __restrict__ psum, float* __restrict__ pmax)
{
    int blk = blockIdx.x;
    if (blk == 512) {  // mu_t[m][b] = mu[b][m]
        for (int e = threadIdx.x; e < MU_ * B_; e += 192) {
            int m = e >> 4, b = e & 15;
            mu_t[e] = mu[b * MU_ + m];
        }
        return;
    }
    int b = blk >> 5, c = blk & 31;
    int d4 = threadIdx.x << 2;
    const float* xp = x + ((size_t)(b * N_ + c * 32)) * D_ + d4;
    float s0 = 0.f, s1 = 0.f, s2 = 0.f, s3 = 0.f;
    float m0 = -3.4e38f, m1 = -3.4e38f, m2 = -3.4e38f, m3 = -3.4e38f;
    for (int n = 0; n < 32; ++n) {
        float4 v = *(const float4*)(xp + (size_t)n * D_);
        s0 += v.x; s1 += v.y; s2 += v.z; s3 += v.w;
        m0 = fmaxf(m0, v.x); m1 = fmaxf(m1, v.y);
        m2 = fmaxf(m2, v.z); m3 = fmaxf(m3, v.w);
    }
    size_t o = ((size_t)(c * B_ + b)) * D_ + d4;
    float4 sv = { s0, s1, s2, s3 }; *(float4*)(psum + o) = sv;
    float4 mv = { m0, m1, m2, m3 }; *(float4*)(pmax + o) = mv;
}

// ---------------------------------------------------------------------------
// k_hyper: partial[b][j] = sum_{m in half} mu[b][m]*M[m][j] (no bias here).
// 588 blocks x 128 thr (2 waves). Block: one K-half (384 rows) x 256 cols of
// one matrix. Waves split b (8 each). Per wave: private 8-slot x 1 KB LDS DMA
// ring for W rows; mu via s_load (uniform). acc = 8 x float4.
#define ACCFMA(C, MV) \
    acc[C].x = fmaf(MV, wv.x, acc[C].x); \
    acc[C].y = fmaf(MV, wv.y, acc[C].y); \
    acc[C].z = fmaf(MV, wv.z, acc[C].z); \
    acc[C].w = fmaf(MV, wv.w, acc[C].w);

#define CONSUME(R) \
    { \
        float4 wv = *(const float4*)&ring[w][(R) & 7][ln << 2]; \
        const float* mup = mu_t + (size_t)(m0 + (R)) * 16 + b0u; \
        float4 mA = *(const float4*)mup; \
        float4 mB = *(const float4*)(mup + 4); \
        ACCFMA(0, mA.x) ACCFMA(1, mA.y) ACCFMA(2, mA.z) ACCFMA(3, mA.w) \
        ACCFMA(4, mB.x) ACCFMA(5, mB.y) ACCFMA(6, mB.z) ACCFMA(7, mB.w) \
    }

__global__ __launch_bounds__(128, 4) void k_hyper(
    const float* __restrict__ Wg1, const float* __restrict__ Wg2,
    const float* __restrict__ Wgs, const float* __restrict__ Bg2,
    const float* __restrict__ mu_t,
    float* __restrict__ w1p, float* __restrict__ w2p,
    float* __restrict__ wsp, float* __restrict__ b2p)
{
    __shared__ float ring[2][8][256];   // 16 KB: per-wave 8-slot x 1 KB ring
    int t = blockIdx.x, tid = threadIdx.x;
    int w = tid >> 6, ln = tid & 63;

    const float* mat; float* outp; int ncols, h, tile;
    if (t < 576) {
        int mi = t >= 288; int tt = t - (mi ? 288 : 0);
        h = tt / 144; tile = tt % 144;
        mat = mi ? Wg2 : Wg1;
        outp = (mi ? w2p : w1p) + (size_t)h * 589824;
        ncols = 36864;
    } else if (t < 582) {
        int u = t - 576; h = u / 3; tile = u % 3;
        mat = Wgs; outp = wsp + (size_t)h * 12288; ncols = 768;
    } else {
        int u = t - 582; h = u / 3; tile = u % 3;
        mat = Bg2; outp = b2p + (size_t)h * 12288; ncols = 768;
    }
    int colbase = tile << 8;
    int m0 = h * 384;
    int b0 = w << 3;
    int b0u = __builtin_amdgcn_readfirstlane(b0);

    const float* gl = mat + (size_t)m0 * ncols + colbase + (ln << 2);

    float4 acc[8];
    #pragma unroll
    for (int i = 0; i < 8; ++i) acc[i] = make_float4(0.f, 0.f, 0.f, 0.f);

    // prologue: fill the ring (8 DMAs in flight)
    #pragma unroll
    for (int s = 0; s < 8; ++s) dma16(gl + (size_t)s * ncols, &ring[w][s][0]);

    // steady state: wait oldest -> consume -> refill same slot
    #pragma unroll 8
    for (int r = 0; r < 376; ++r) {
        asm volatile("s_waitcnt vmcnt(7)" ::: "memory");
        CONSUME(r)
        __builtin_amdgcn_sched_barrier(0);
        dma16(gl + (size_t)(r + 8) * ncols, &ring[w][r & 7][0]);
    }
    // tail: drain
    asm volatile("s_waitcnt vmcnt(0)" ::: "memory");
    #pragma unroll
    for (int r = 376; r < 384; ++r) { CONSUME(r) }

    #pragma unroll
    for (int i = 0; i < 8; ++i)
        *(float4*)(outp + (size_t)(b0 + i) * ncols + colbase + (ln << 2)) = acc[i];
}

// ---------------------------------------------------------------------------
// k_redW: merge the two K-half partials + bias for W1/W2/Ws/b2. 1176 x 256.
__global__ __launch_bounds__(256) void k_redW(
    const float* __restrict__ w1p, const float* __restrict__ w2p,
    const float* __restrict__ wsp, const float* __restrict__ b2p,
    const float* __restrict__ bg1, const float* __restrict__ bg2,
    const float* __restrict__ bgs, const float* __restrict__ bb2,
    float* __restrict__ w1, float* __restrict__ w2,
    float* __restrict__ wsw, float* __restrict__ b2v)
{
    int i4 = blockIdx.x * 256 + threadIdx.x;
    const float* src; const float* bias; float* dst; int loc, bcols4;
    if (i4 < 147456)       { src = w1p; bias = bg1; dst = w1;  loc = i4;          bcols4 = 9216; }
    else if (i4 < 294912)  { src = w2p; bias = bg2; dst = w2;  loc = i4 - 147456; bcols4 = 9216; }
    else if (i4 < 297984)  { src = wsp; bias = bgs; dst = wsw; loc = i4 - 294912; bcols4 = 192; }
    else                   { src = b2p; bias = bb2; dst = b2v; loc = i4 - 297984; bcols4 = 192; }
    int half_stride4 = bcols4 * 16;   // floats/4 per half
    float4 a = ((const float4*)src)[loc];
    float4 b = ((const float4*)src)[loc + half_stride4];
    float4 bi = ((const float4*)bias)[loc % bcols4];
    float4 o = { a.x + b.x + bi.x, a.y + b.y + bi.y,
                 a.z + b.z + bi.z, a.w + b.w + bi.w };
    ((float4*)dst)[loc] = o;
}

// ---------------------------------------------------------------------------
// k_red: finalize avg/max pooling (96 blocks); tile 0 also computes
// bs[b] = dot(mu[b], Bgs) + bbs.
__global__ __launch_bounds__(128) void k_red(
    const float* __restrict__ psum, const float* __restrict__ pmax,
    const float* __restrict__ mu, const float* __restrict__ Bgs,
    const float* __restrict__ bbs,
    float* __restrict__ avgb, float* __restrict__ maxb, float* __restrict__ bs)
{
    int b = blockIdx.x / 6, tile = blockIdx.x % 6, tid = threadIdx.x;
    int d = tile * 128 + tid;
    float s = 0.f, mx = -3.4e38f;
    for (int c = 0; c < 32; ++c) {
        size_t idx = ((size_t)(c * B_ + b)) * D_ + d;
        s += psum[idx];
        mx = fmaxf(mx, pmax[idx]);
    }
    avgb[b * D_ + d] = s * (1.f / 1024.f);
    maxb[b * D_ + d] = mx;

    if (tile == 0) {
        __shared__ float sb[128];
        float p = 0.f;
        for (int m = tid; m < MU_; m += 128) p += mu[b * MU_ + m] * Bgs[m];
        sb[tid] = p;
        __syncthreads();
        if (tid < 64) {
            float v = sb[tid] + sb[tid + 64];
            #pragma unroll
            for (int k = 32; k; k >>= 1) v += __shfl_xor(v, k, 64);
            if (tid == 0) bs[b] = v + bbs[0];
        }
    }
}

// ---------------------------------------------------------------------------
// k_c1: g[b][o] = relu(W1[b,o]@avg + b1) + relu(W1[b,o]@max + b1),
// b1 = dot(mu[b], Bg1[:,o]) + bb1[o] folded in. grid 768 x 64 (1 wave).
__global__ __launch_bounds__(64) void k_c1(
    const float* __restrict__ w1, const float* __restrict__ avgb,
    const float* __restrict__ maxb, const float* __restrict__ mu,
    const float* __restrict__ Bg1, const float* __restrict__ bb1,
    float* __restrict__ g)
{
    int b = blockIdx.x / 48, o = blockIdx.x % 48, ln = threadIdx.x;
    const float* row = w1 + (size_t)b * 36864 + o * 768;
    const float* av  = avgb + b * D_;
    const float* mxp = maxb + b * D_;
    const float* mub = mu + b * MU_;
    float pa = 0.f, pm = 0.f, pb = 0.f;
    #pragma unroll
    for (int i = 0; i < 12; ++i) {
        int idx = ln + (i << 6);
        float wv = row[idx];
        pa += wv * av[idx];
        pm += wv * mxp[idx];
        pb += Bg1[(size_t)idx * 48 + o] * mub[idx];
    }
    #pragma unroll
    for (int k = 32; k; k >>= 1) {
        pa += __shfl_xor(pa, k, 64);
        pm += __shfl_xor(pm, k, 64);
        pb += __shfl_xor(pb, k, 64);
    }
    if (ln == 0) {
        float bb = pb + bb1[o];
        g[b * 48 + o] = fmaxf(pa + bb, 0.f) + fmaxf(pm + bb, 0.f);
    }
}

// ---------------------------------------------------------------------------
// k_c2: att = W2[b,d,:]@g[b] + 2*b2[b,d]; cg = sigmoid(att). grid 192 x 64.
__global__ __launch_bounds__(64) void k_c2(
    const float* __restrict__ w2, const float* __restrict__ b2w,
    const float* __restrict__ g, float* __restrict__ cg)
{
    __shared__ float gL[48];
    int b = blockIdx.x / 12, tile = blockIdx.x % 12, ln = threadIdx.x;
    if (ln < 48) gL[ln] = g[b * 48 + ln];
    __syncthreads();
    int d = (tile << 6) + ln;
    const float* row = w2 + (size_t)b * 36864 + d * 48;
    float att = 0.f;
    #pragma unroll
    for (int o = 0; o < 48; o += 4) {
        float4 w4 = *(const float4*)(row + o);
        att += w4.x * gL[o] + w4.y * gL[o + 1] + w4.z * gL[o + 2] + w4.w * gL[o + 3];
    }
    att += 2.f * b2w[b * D_ + d];
    cg[b * D_ + d] = 1.f / (1.f + expf(-att));
}

// ---------------------------------------------------------------------------
// k_final: one wave per token: xg = x*cg; s = dot(xg, Ws)+bs; out = xg*sigmoid(s).
__global__ __launch_bounds__(256) void k_final(
    const float* __restrict__ x, const float* __restrict__ cg,
    const float* __restrict__ wsw, const float* __restrict__ bs,
    float* __restrict__ out)
{
    int wv = threadIdx.x >> 6, ln = threadIdx.x & 63;
    int tok = (blockIdx.x << 2) + wv;
    int b = tok >> 10;
    const float* xp = x + (size_t)tok * D_;
    const float* cp = cg + b * D_;
    const float* wp = wsw + b * D_;
    float xg[12];
    float part = 0.f;
    #pragma unroll
    for (int q = 0; q < 3; ++q) {
        int d = (q << 8) + (ln << 2);
        float4 xv = *(const float4*)(xp + d);
        float4 cv = *(const float4*)(cp + d);
        float4 w4 = *(const float4*)(wp + d);
        float g0 = xv.x * cv.x, g1 = xv.y * cv.y;
        float g2 = xv.z * cv.z, g3 = xv.w * cv.w;
        part += g0 * w4.x + g1 * w4.y + g2 * w4.z + g3 * w4.w;
        xg[q * 4 + 0] = g0; xg[q * 4 + 1] = g1;
        xg[q * 4 + 2] = g2; xg[q * 4 + 3] = g3;
    }
    #pragma unroll
    for (int k = 32; k; k >>= 1) part += __shfl_xor(part, k, 64);
    float s = part + bs[b];
    float sig = 1.f / (1.f + expf(-s));
    #pragma unroll
    for (int q = 0; q < 3; ++q) {
        int d = (q << 8) + (ln << 2);
        float4 o4 = { xg[q * 4 + 0] * sig, xg[q * 4 + 1] * sig,
                      xg[q * 4 + 2] * sig, xg[q * 4 + 3] * sig };
        *(float4*)(out + (size_t)tok * D_ + d) = o4;
    }
}

// ---------------------------------------------------------------------------
extern "C" void kernel_launch(void* const* d_in, const int* in_sizes, int n_in,
                              void* d_out, int out_size, void* d_ws, size_t ws_size,
                              hipStream_t stream)
{
    const float* x   = (const float*)d_in[0];
    const float* mu  = (const float*)d_in[1];
    const float* Wg1 = (const float*)d_in[2];
    const float* bg1 = (const float*)d_in[3];
    const float* Bg1 = (const float*)d_in[4];
    const float* bb1 = (const float*)d_in[5];
    const float* Wg2 = (const float*)d_in[6];
    const float* bg2 = (const float*)d_in[7];
    const float* Bg2 = (const float*)d_in[8];
    const float* bb2 = (const float*)d_in[9];
    const float* Wgs = (const float*)d_in[10];
    const float* bgs = (const float*)d_in[11];
    const float* Bgs = (const float*)d_in[12];
    const float* bbs = (const float*)d_in[13];
    float* base = (float*)d_ws;
    float* out  = (float*)d_out;

    float* mu_t = base;                  // 12288
    float* psum = mu_t + 12288;          // 393216
    float* pmax = psum + 393216;         // 393216
    float* w1p  = pmax + 393216;         // 2*589824
    float* w2p  = w1p  + 1179648;        // 2*589824
    float* wsp  = w2p  + 1179648;        // 2*12288
    float* b2p  = wsp  + 24576;          // 2*12288
    float* w1   = b2p  + 24576;          // 589824
    float* w2   = w1   + 589824;         // 589824
    float* wsw  = w2   + 589824;         // 12288
    float* b2v  = wsw  + 12288;          // 12288
    float* avgb = b2v  + 12288;          // 12288
    float* maxb = avgb + 12288;          // 12288
    float* g    = maxb + 12288;          // 768
    float* bs   = g    + 768;            // 16
    float* cg   = bs   + 16;             // 12288

    hipLaunchKernelGGL(k_pool,  dim3(513),  dim3(192), 0, stream, x, mu, mu_t, psum, pmax);
    hipLaunchKernelGGL(k_hyper, dim3(588),  dim3(128), 0, stream,
                       Wg1, Wg2, Wgs, Bg2, mu_t, w1p, w2p, wsp, b2p);
    hipLaunchKernelGGL(k_redW,  dim3(1176), dim3(256), 0, stream,
                       w1p, w2p, wsp, b2p, bg1, bg2, bgs, bb2, w1, w2, wsw, b2v);
    hipLaunchKernelGGL(k_red,   dim3(96),   dim3(128), 0, stream,
                       psum, pmax, mu, Bgs, bbs, avgb, maxb, bs);
    hipLaunchKernelGGL(k_c1,    dim3(768),  dim3(64),  0, stream,
                       w1, avgb, maxb, mu, Bg1, bb1, g);
    hipLaunchKernelGGL(k_c2,    dim3(192),  dim3(64),  0, stream, w2, b2v, g, cg);
    hipLaunchKernelGGL(k_final, dim3(4096), dim3(256), 0, stream, x, cg, wsw, bs, out);
}

// Round 7
// 112.028 us; speedup vs baseline: 2.4394x; 2.4394x over previous
//
#include <hip/hip_runtime.h>
#include <math.h>

// QueryDynamicAttention: B=16, N=1024, D=768, MU=768, R=16, DR=48
// out = (x * sigmoid(channel_att)) * sigmoid(spatial)
// Hypernet GEMM (mu @ Wg*, 226 MB streamed) is HBM-bound. Round 7:
// k_hyper rebuilt as the PROVEN 2-phase template (m97/m230): double-buffered
// 32-row x 128-col tiles staged via global_load_lds DMA (W 16 KB + mu 2 KB),
// ONE vmcnt(0)+barrier per tile, compute entirely from LDS. acc[8]/thread
// (b-split 8/8) keeps VGPR tiny; 36 KB LDS -> 4 blocks/CU.

#define B_  16
#define N_  1024
#define D_  768
#define MU_ 768

__device__ __forceinline__ void dma16(const float* g, float* l) {
    __builtin_amdgcn_global_load_lds(
        (__attribute__((address_space(1))) void*)(g),
        (__attribute__((address_space(3))) void*)(l), 16, 0, 0);
}

// ---------------------------------------------------------------------------
// k_pool: avg/max pooling partials over N (32 chunks of 32 tokens) + mu transpose
__global__ __launch_bounds__(192) void k_pool(
    const float* __restrict__ x, const float* __restrict__ mu,
    float* __restrict__ mu_t, float* __restrict__ psum, float* __restrict__ pmax)
{
    int blk = blockIdx.x;
    if (blk == 512) {  // mu_t[m][b] = mu[b][m]
        for (int e = threadIdx.x; e < MU_ * B_; e += 192) {
            int m = e >> 4, b = e & 15;
            mu_t[e] = mu[b * MU_ + m];
        }
        return;
    }
    int b = blk >> 5, c = blk & 31;
    int d4 = threadIdx.x << 2;
    const float* xp = x + ((size_t)(b * N_ + c * 32)) * D_ + d4;
    float s0 = 0.f, s1 = 0.f, s2 = 0.f, s3 = 0.f;
    float m0 = -3.4e38f, m1 = -3.4e38f, m2 = -3.4e38f, m3 = -3.4e38f;
    for (int n = 0; n < 32; ++n) {
        float4 v = *(const float4*)(xp + (size_t)n * D_);
        s0 += v.x; s1 += v.y; s2 += v.z; s3 += v.w;
        m0 = fmaxf(m0, v.x); m1 = fmaxf(m1, v.y);
        m2 = fmaxf(m2, v.z); m3 = fmaxf(m3, v.w);
    }
    size_t o = ((size_t)(c * B_ + b)) * D_ + d4;
    float4 sv = { s0, s1, s2, s3 }; *(float4*)(psum + o) = sv;
    float4 mv = { m0, m1, m2, m3 }; *(float4*)(pmax + o) = mv;
}

// ---------------------------------------------------------------------------
// k_hyper: out[b][j] = sum_m mu[b][m]*M[m][j] + bias[j] for Wg1/Wg2/Wgs/Bg2.
// 588 blocks x 256 thr (4 waves). Block: 128 cols, loop 24 tiles of 32 rows.
// Per tile: stage W[32][128] (16 KB, 16 wave-DMAs: unit u=w*4+i covers rows
// {2u,2u+1}) + mu_t[32][16] (2 KB, wave 0) into buf^1 while computing buf.
// Thread: col c=tid&127, b-half bh=tid>>7, acc[8].
__global__ __launch_bounds__(256, 4) void k_hyper(
    const float* __restrict__ Wg1, const float* __restrict__ bg1,
    const float* __restrict__ Wg2, const float* __restrict__ bg2,
    const float* __restrict__ Wgs, const float* __restrict__ bgs,
    const float* __restrict__ Bg2, const float* __restrict__ bb2,
    const float* __restrict__ mu_t,
    float* __restrict__ w1o, float* __restrict__ w2o,
    float* __restrict__ wso, float* __restrict__ b2o)
{
    __shared__ __align__(16) float ldsW[2][32 * 128];   // 32 KB
    __shared__ __align__(16) float ldsMu[2][32 * 16];   // 4 KB
    int t = blockIdx.x, tid = threadIdx.x;
    int w = tid >> 6, ln = tid & 63;

    const float* mat; const float* bias; float* outp; int ncols; int tile;
    if (t < 288)      { mat = Wg1; bias = bg1; outp = w1o; ncols = 36864; tile = t; }
    else if (t < 576) { mat = Wg2; bias = bg2; outp = w2o; ncols = 36864; tile = t - 288; }
    else if (t < 582) { mat = Wgs; bias = bgs; outp = wso; ncols = 768;   tile = t - 576; }
    else              { mat = Bg2; bias = bb2; outp = b2o; ncols = 768;   tile = t - 582; }
    int colbase = tile << 7;

    // staging source: wave w, unit i (u = w*4+i) covers rows 8w+2i+(ln>>5),
    // cols colbase + (ln&31)*4 .. +4
    const float* srcW = mat + (size_t)((w << 3) + (ln >> 5)) * ncols
                            + colbase + ((ln & 31) << 2);
    const float* srcMu = mu_t + (ln << 2);
    float* dstW0 = &ldsW[0][w << 10];
    float* dstW1 = &ldsW[1][w << 10];

    #define STAGE(BUF, TT) { \
        const float* s_ = srcW + (size_t)((TT) * 32) * ncols; \
        float* d_ = (BUF) ? dstW1 : dstW0; \
        dma16(s_,                       d_);       \
        dma16(s_ + (size_t)2 * ncols,   d_ + 256); \
        dma16(s_ + (size_t)4 * ncols,   d_ + 512); \
        dma16(s_ + (size_t)6 * ncols,   d_ + 768); \
        if (w == 0) { \
            const float* sm_ = srcMu + (TT) * 512; \
            dma16(sm_,       &ldsMu[BUF][0]);   \
            dma16(sm_ + 256, &ldsMu[BUF][256]); \
        } \
    }

    int c  = tid & 127;
    int bh = tid >> 7;          // 0/1 -> batches 8*bh .. 8*bh+7
    float acc[8];
    #pragma unroll
    for (int i = 0; i < 8; ++i) acc[i] = 0.f;

    // prologue
    STAGE(0, 0)
    asm volatile("s_waitcnt vmcnt(0)" ::: "memory");
    __syncthreads();

    for (int tt = 0; tt < 24; ++tt) {
        int cur = tt & 1;
        if (tt < 23) STAGE(cur ^ 1, tt + 1)
        const float* Wb  = &ldsW[cur][0];
        const float* Mb  = &ldsMu[cur][bh << 3];
        #pragma unroll
        for (int m = 0; m < 32; ++m) {
            float wv = Wb[m * 128 + c];
            float4 mA = *(const float4*)(Mb + m * 16);
            float4 mB = *(const float4*)(Mb + m * 16 + 4);
            acc[0] = fmaf(mA.x, wv, acc[0]);
            acc[1] = fmaf(mA.y, wv, acc[1]);
            acc[2] = fmaf(mA.z, wv, acc[2]);
            acc[3] = fmaf(mA.w, wv, acc[3]);
            acc[4] = fmaf(mB.x, wv, acc[4]);
            acc[5] = fmaf(mB.y, wv, acc[5]);
            acc[6] = fmaf(mB.z, wv, acc[6]);
            acc[7] = fmaf(mB.w, wv, acc[7]);
        }
        asm volatile("s_waitcnt vmcnt(0)" ::: "memory");
        __syncthreads();
    }
    #undef STAGE

    float bv = bias[colbase + c];
    #pragma unroll
    for (int i = 0; i < 8; ++i)
        outp[(size_t)((bh << 3) + i) * ncols + colbase + c] = acc[i] + bv;
}

// ---------------------------------------------------------------------------
// k_red: finalize avg/max pooling (96 blocks); tile 0 also computes
// bs[b] = dot(mu[b], Bgs) + bbs.
__global__ __launch_bounds__(128) void k_red(
    const float* __restrict__ psum, const float* __restrict__ pmax,
    const float* __restrict__ mu, const float* __restrict__ Bgs,
    const float* __restrict__ bbs,
    float* __restrict__ avgb, float* __restrict__ maxb, float* __restrict__ bs)
{
    int b = blockIdx.x / 6, tile = blockIdx.x % 6, tid = threadIdx.x;
    int d = tile * 128 + tid;
    float s = 0.f, mx = -3.4e38f;
    for (int c = 0; c < 32; ++c) {
        size_t idx = ((size_t)(c * B_ + b)) * D_ + d;
        s += psum[idx];
        mx = fmaxf(mx, pmax[idx]);
    }
    avgb[b * D_ + d] = s * (1.f / 1024.f);
    maxb[b * D_ + d] = mx;

    if (tile == 0) {
        __shared__ float sb[128];
        float p = 0.f;
        for (int m = tid; m < MU_; m += 128) p += mu[b * MU_ + m] * Bgs[m];
        sb[tid] = p;
        __syncthreads();
        if (tid < 64) {
            float v = sb[tid] + sb[tid + 64];
            #pragma unroll
            for (int k = 32; k; k >>= 1) v += __shfl_xor(v, k, 64);
            if (tid == 0) bs[b] = v + bbs[0];
        }
    }
}

// ---------------------------------------------------------------------------
// k_c1: g[b][o] = relu(W1[b,o]@avg + b1) + relu(W1[b,o]@max + b1),
// b1 = dot(mu[b], Bg1[:,o]) + bb1[o] folded in. grid 768 x 64 (1 wave).
__global__ __launch_bounds__(64) void k_c1(
    const float* __restrict__ w1, const float* __restrict__ avgb,
    const float* __restrict__ maxb, const float* __restrict__ mu,
    const float* __restrict__ Bg1, const float* __restrict__ bb1,
    float* __restrict__ g)
{
    int b = blockIdx.x / 48, o = blockIdx.x % 48, ln = threadIdx.x;
    const float* row = w1 + (size_t)b * 36864 + o * 768;
    const float* av  = avgb + b * D_;
    const float* mxp = maxb + b * D_;
    const float* mub = mu + b * MU_;
    float pa = 0.f, pm = 0.f, pb = 0.f;
    #pragma unroll
    for (int i = 0; i < 12; ++i) {
        int idx = ln + (i << 6);
        float wv = row[idx];
        pa += wv * av[idx];
        pm += wv * mxp[idx];
        pb += Bg1[(size_t)idx * 48 + o] * mub[idx];
    }
    #pragma unroll
    for (int k = 32; k; k >>= 1) {
        pa += __shfl_xor(pa, k, 64);
        pm += __shfl_xor(pm, k, 64);
        pb += __shfl_xor(pb, k, 64);
    }
    if (ln == 0) {
        float bb = pb + bb1[o];
        g[b * 48 + o] = fmaxf(pa + bb, 0.f) + fmaxf(pm + bb, 0.f);
    }
}

// ---------------------------------------------------------------------------
// k_c2: att = W2[b,d,:]@g[b] + 2*b2[b,d]; cg = sigmoid(att). grid 192 x 64.
__global__ __launch_bounds__(64) void k_c2(
    const float* __restrict__ w2, const float* __restrict__ b2w,
    const float* __restrict__ g, float* __restrict__ cg)
{
    __shared__ float gL[48];
    int b = blockIdx.x / 12, tile = blockIdx.x % 12, ln = threadIdx.x;
    if (ln < 48) gL[ln] = g[b * 48 + ln];
    __syncthreads();
    int d = (tile << 6) + ln;
    const float* row = w2 + (size_t)b * 36864 + d * 48;
    float att = 0.f;
    #pragma unroll
    for (int o = 0; o < 48; o += 4) {
        float4 w4 = *(const float4*)(row + o);
        att += w4.x * gL[o] + w4.y * gL[o + 1] + w4.z * gL[o + 2] + w4.w * gL[o + 3];
    }
    att += 2.f * b2w[b * D_ + d];
    cg[b * D_ + d] = 1.f / (1.f + expf(-att));
}

// ---------------------------------------------------------------------------
// k_final: one wave per token: xg = x*cg; s = dot(xg, Ws)+bs; out = xg*sigmoid(s).
__global__ __launch_bounds__(256) void k_final(
    const float* __restrict__ x, const float* __restrict__ cg,
    const float* __restrict__ wsw, const float* __restrict__ bs,
    float* __restrict__ out)
{
    int wv = threadIdx.x >> 6, ln = threadIdx.x & 63;
    int tok = (blockIdx.x << 2) + wv;
    int b = tok >> 10;
    const float* xp = x + (size_t)tok * D_;
    const float* cp = cg + b * D_;
    const float* wp = wsw + b * D_;
    float xg[12];
    float part = 0.f;
    #pragma unroll
    for (int q = 0; q < 3; ++q) {
        int d = (q << 8) + (ln << 2);
        float4 xv = *(const float4*)(xp + d);
        float4 cv = *(const float4*)(cp + d);
        float4 w4 = *(const float4*)(wp + d);
        float g0 = xv.x * cv.x, g1 = xv.y * cv.y;
        float g2 = xv.z * cv.z, g3 = xv.w * cv.w;
        part += g0 * w4.x + g1 * w4.y + g2 * w4.z + g3 * w4.w;
        xg[q * 4 + 0] = g0; xg[q * 4 + 1] = g1;
        xg[q * 4 + 2] = g2; xg[q * 4 + 3] = g3;
    }
    #pragma unroll
    for (int k = 32; k; k >>= 1) part += __shfl_xor(part, k, 64);
    float s = part + bs[b];
    float sig = 1.f / (1.f + expf(-s));
    #pragma unroll
    for (int q = 0; q < 3; ++q) {
        int d = (q << 8) + (ln << 2);
        float4 o4 = { xg[q * 4 + 0] * sig, xg[q * 4 + 1] * sig,
                      xg[q * 4 + 2] * sig, xg[q * 4 + 3] * sig };
        *(float4*)(out + (size_t)tok * D_ + d) = o4;
    }
}

// ---------------------------------------------------------------------------
extern "C" void kernel_launch(void* const* d_in, const int* in_sizes, int n_in,
                              void* d_out, int out_size, void* d_ws, size_t ws_size,
                              hipStream_t stream)
{
    const float* x   = (const float*)d_in[0];
    const float* mu  = (const float*)d_in[1];
    const float* Wg1 = (const float*)d_in[2];
    const float* bg1 = (const float*)d_in[3];
    const float* Bg1 = (const float*)d_in[4];
    const float* bb1 = (const float*)d_in[5];
    const float* Wg2 = (const float*)d_in[6];
    const float* bg2 = (const float*)d_in[7];
    const float* Bg2 = (const float*)d_in[8];
    const float* bb2 = (const float*)d_in[9];
    const float* Wgs = (const float*)d_in[10];
    const float* bgs = (const float*)d_in[11];
    const float* Bgs = (const float*)d_in[12];
    const float* bbs = (const float*)d_in[13];
    float* base = (float*)d_ws;
    float* out  = (float*)d_out;

    float* mu_t = base;                  // 12288
    float* psum = mu_t + 12288;          // 393216
    float* pmax = psum + 393216;         // 393216
    float* w1   = pmax + 393216;         // 589824
    float* w2   = w1   + 589824;         // 589824
    float* wsw  = w2   + 589824;         // 12288
    float* b2   = wsw  + 12288;          // 12288
    float* avgb = b2   + 12288;          // 12288
    float* maxb = avgb + 12288;          // 12288
    float* g    = maxb + 12288;          // 768
    float* bs   = g    + 768;            // 16
    float* cg   = bs   + 16;             // 12288

    hipLaunchKernelGGL(k_pool,  dim3(513),  dim3(192), 0, stream, x, mu, mu_t, psum, pmax);
    hipLaunchKernelGGL(k_hyper, dim3(588),  dim3(256), 0, stream,
                       Wg1, bg1, Wg2, bg2, Wgs, bgs, Bg2, bb2,
                       mu_t, w1, w2, wsw, b2);
    hipLaunchKernelGGL(k_red,   dim3(96),   dim3(128), 0, stream,
                       psum, pmax, mu, Bgs, bbs, avgb, maxb, bs);
    hipLaunchKernelGGL(k_c1,    dim3(768),  dim3(64),  0, stream,
                       w1, avgb, maxb, mu, Bg1, bb1, g);
    hipLaunchKernelGGL(k_c2,    dim3(192),  dim3(64),  0, stream, w2, b2, g, cg);
    hipLaunchKernelGGL(k_final, dim3(4096), dim3(256), 0, stream, x, cg, wsw, bs, out);
}